// Round 4
// baseline (449.471 us; speedup 1.0000x reference)
//
#include <hip/hip_runtime.h>

// Fused 2-layer GRU + FC for (B=4096, L=128, IN=16, H=128, NC=24).
// 256 blocks x 512 threads (1 block/CU); block = 16 batch rows, wave w owns
// h-cols [16w,16w+16). Layer2 runs one step behind layer1 => single barrier
// per step, 39 independent MFMAs of ILP per barrier interval.
//
// Register budget at 2 waves/SIMD: 256/wave unified = 128 arch VGPR + 128 AGPR.
// Weight fragments = 156 regs -> CANNOT fit in arch class alone (round 3: "v"
// pins forced 156 live arch regs -> scratch spill + per-step reloads, 52%
// VALUBusy). Fix: pin exactly 128 regs of fragments into AGPRs ("a" class,
// MFMA reads A/B from AGPR on gfx950) and the remaining 28 into arch VGPRs.

typedef _Float16 half_t;
typedef _Float16 half8 __attribute__((ext_vector_type(8)));
typedef _Float16 half4v __attribute__((ext_vector_type(4)));
typedef float f32x4 __attribute__((ext_vector_type(4)));

#define BB 16      // batch rows per block
#define HS 136     // h row stride (halves)
#define XS 520     // x chunk row stride (halves): 32*16 + 8 pad

static __device__ __forceinline__ f32x4 mfma16(half8 a, half8 b, f32x4 c) {
  return __builtin_amdgcn_mfma_f32_16x16x32_f16(a, b, c, 0, 0, 0);
}

// Pin into the AGPR file (128 regs idle otherwise; MFMA reads B from AGPR).
static __device__ __forceinline__ void pinA(half8& v) {
  f32x4 t = __builtin_bit_cast(f32x4, v);
  asm volatile("" : "+a"(t));
  v = __builtin_bit_cast(half8, t);
}
// Pin into arch VGPRs (for the <=28 leftover weight regs).
static __device__ __forceinline__ void pinV(half8& v) {
  f32x4 t = __builtin_bit_cast(f32x4, v);
  asm volatile("" : "+v"(t));
  v = __builtin_bit_cast(half8, t);
}

static __device__ __forceinline__ half8 zero8() {
  half8 v;
#pragma unroll
  for (int i = 0; i < 8; ++i) v[i] = (half_t)0.f;
  return v;
}

static __device__ __forceinline__ half8 ldw8(const float* __restrict__ p) {
  float4 a = *(const float4*)p;
  float4 b = *(const float4*)(p + 4);
  half8 r;
  r[0] = (half_t)a.x; r[1] = (half_t)a.y; r[2] = (half_t)a.z; r[3] = (half_t)a.w;
  r[4] = (half_t)b.x; r[5] = (half_t)b.y; r[6] = (half_t)b.z; r[7] = (half_t)b.w;
  return r;
}

static __device__ __forceinline__ float sigm(float v) {
  return __builtin_amdgcn_rcpf(1.f + __expf(-v));
}
static __device__ __forceinline__ float tanh_fast(float v) {
  float e = __expf(2.f * v);
  return 1.f - 2.f * __builtin_amdgcn_rcpf(1.f + e);
}

__global__ __launch_bounds__(512, 2) void gru_fused(
    const float* __restrict__ x,                                    // (4096,2,1024)
    const float* __restrict__ wih1, const float* __restrict__ whh1, // (384,16),(384,128)
    const float* __restrict__ bih1, const float* __restrict__ bhh1,
    const float* __restrict__ wih2, const float* __restrict__ whh2, // (384,128)x2
    const float* __restrict__ bih2, const float* __restrict__ bhh2,
    const float* __restrict__ fcw, const float* __restrict__ fcb,   // (24,128),(24,)
    float* __restrict__ out)                                        // (4096,24)
{
  __shared__ __align__(16) half_t xl[BB][XS];        // 16640 B
  __shared__ __align__(16) half_t h1b[2][BB][HS];    //  8704 B
  __shared__ __align__(16) half_t h2b[2][BB][HS];    //  8704 B
  __shared__ float h2f[BB][129];                     //  8256 B

  const int tid = threadIdx.x;
  const int lane = tid & 63;
  const int wv = tid >> 6;      // wave 0..7
  const int q = lane >> 4;      // quad 0..3
  const int c = lane & 15;
  const int jc = wv * 16 + c;   // this lane's h-column (0..127)
  const int s0 = blockIdx.x * BB;

  // zero both parity buffers of both states (layer2 MFMAs run unguarded at i=0)
  for (int i = tid; i < 2 * BB * HS; i += 512) {
    ((half_t*)h1b)[i] = (half_t)0.f;
    ((half_t*)h2b)[i] = (half_t)0.f;
  }

  // biases (r/z fold b_ih+b_hh; n keeps them split for r*(Wh+b_hh) semantics)
  const float b1r  = bih1[jc]       + bhh1[jc];
  const float b1z  = bih1[128 + jc] + bhh1[128 + jc];
  const float b1in = bih1[256 + jc];
  const float b1hn = bhh1[256 + jc];
  const float b2r  = bih2[jc]       + bhh2[jc];
  const float b2z  = bih2[128 + jc] + bhh2[128 + jc];
  const float b2in = bih2[256 + jc];
  const float b2hn = bhh2[256 + jc];

  // weight B-fragments: lane holds W[n=jc(+g*128)][k = kk*32 + q*8 + j]
  half8 wi1r, wi1z, wi1n;
  if (q < 2) {  // real K=16, quads 2..3 are zero-pad
    wi1r = ldw8(wih1 + (0 * 128 + jc) * 16 + q * 8);
    wi1z = ldw8(wih1 + (1 * 128 + jc) * 16 + q * 8);
    wi1n = ldw8(wih1 + (2 * 128 + jc) * 16 + q * 8);
  } else {
    wi1r = zero8(); wi1z = zero8(); wi1n = zero8();
  }
  pinV(wi1r); pinV(wi1z); pinV(wi1n);

  half8 wh1r[4], wh1z[4], wh1n[4], wi2r[4], wi2z[4], wi2n[4], wh2r[4], wh2z[4], wh2n[4];
#pragma unroll
  for (int kk = 0; kk < 4; ++kk) {
    const int ko = kk * 32 + q * 8;
    // AGPR-pinned set: 32 frags = 128 AGPRs exactly
    wh1r[kk] = ldw8(whh1 + (0 * 128 + jc) * 128 + ko);  pinA(wh1r[kk]);
    wh1z[kk] = ldw8(whh1 + (1 * 128 + jc) * 128 + ko);  pinA(wh1z[kk]);
    wh1n[kk] = ldw8(whh1 + (2 * 128 + jc) * 128 + ko);  pinA(wh1n[kk]);
    wi2r[kk] = ldw8(wih2 + (0 * 128 + jc) * 128 + ko);  pinA(wi2r[kk]);
    wi2z[kk] = ldw8(wih2 + (1 * 128 + jc) * 128 + ko);  pinA(wi2z[kk]);
    wh2r[kk] = ldw8(whh2 + (0 * 128 + jc) * 128 + ko);  pinA(wh2r[kk]);
    wh2z[kk] = ldw8(whh2 + (1 * 128 + jc) * 128 + ko);  pinA(wh2z[kk]);
    wh2n[kk] = ldw8(whh2 + (2 * 128 + jc) * 128 + ko);  pinA(wh2n[kk]);
    // arch-VGPR set: 4 frags = 16 regs (plus wi1* = 12 above)
    wi2n[kk] = ldw8(wih2 + (2 * 128 + jc) * 128 + ko);  pinV(wi2n[kk]);
  }

  // fp32 hidden state, lane-resident: rows m = 4q+r, col jc
  float h1p[4] = {0.f, 0.f, 0.f, 0.f};
  float h2p[4] = {0.f, 0.f, 0.f, 0.f};

  for (int tc = 0; tc < 4; ++tc) {
    // stage x[s][ch][tc*256 .. +255] -> xl[s][tl*16 + ch*8 + k], fp16
#pragma unroll
    for (int it = 0; it < 4; ++it) {
      int idx = tid + it * 512;         // 0..2047 float4s
      int s = idx >> 7;
      int rem = idx & 127;
      int ch = rem >> 6;
      int i4 = rem & 63;
      const float4 v = *(const float4*)(x + (size_t)(s0 + s) * 2048 + ch * 1024 + tc * 256 + i4 * 4);
      half4v hv;
      hv[0] = (half_t)v.x; hv[1] = (half_t)v.y; hv[2] = (half_t)v.z; hv[3] = (half_t)v.w;
      *(half4v*)&xl[s][(i4 >> 1) * 16 + ch * 8 + (i4 & 1) * 4] = hv;
    }
    __syncthreads();

    for (int tt = 0; tt < 32; ++tt) {
      const int i = tc * 32 + tt;      // layer1 step index; layer2 does step i-1
      const int rb = i & 1;
      const int wb = rb ^ 1;

      f32x4 ar  = {b1r, b1r, b1r, b1r};
      f32x4 az  = {b1z, b1z, b1z, b1z};
      f32x4 ain = {b1in, b1in, b1in, b1in};
      f32x4 ahn = {b1hn, b1hn, b1hn, b1hn};
      f32x4 cr  = {b2r, b2r, b2r, b2r};
      f32x4 cz  = {b2z, b2z, b2z, b2z};
      f32x4 cin = {b2in, b2in, b2in, b2in};
      f32x4 chn = {b2hn, b2hn, b2hn, b2hn};

      {
        half8 ax = zero8();
        if (q < 2) ax = *(const half8*)&xl[c][tt * 16 + q * 8];
        ar  = mfma16(ax, wi1r, ar);
        az  = mfma16(ax, wi1z, az);
        ain = mfma16(ax, wi1n, ain);
      }
#pragma unroll
      for (int kk = 0; kk < 4; ++kk) {
        half8 ah = *(const half8*)&h1b[rb][c][kk * 32 + q * 8];  // h1[i-1]
        half8 a2 = *(const half8*)&h2b[rb][c][kk * 32 + q * 8];  // h2[i-2]
        ar  = mfma16(ah, wh1r[kk], ar);
        az  = mfma16(ah, wh1z[kk], az);
        ahn = mfma16(ah, wh1n[kk], ahn);
        cr  = mfma16(ah, wi2r[kk], cr);   // layer2 input = h1[i-1]
        cz  = mfma16(ah, wi2z[kk], cz);
        cin = mfma16(ah, wi2n[kk], cin);
        cr  = mfma16(a2, wh2r[kk], cr);
        cz  = mfma16(a2, wh2z[kk], cz);
        chn = mfma16(a2, wh2n[kk], chn);
      }

      // layer1 epilogue: h1[i]
#pragma unroll
      for (int r = 0; r < 4; ++r) {
        float rg = sigm(ar[r]);
        float zg = sigm(az[r]);
        float ng = tanh_fast(fmaf(rg, ahn[r], ain[r]));
        float hn = fmaf(zg, h1p[r] - ng, ng);   // (1-z)*n + z*h
        h1p[r] = hn;
        h1b[wb][q * 4 + r][jc] = (half_t)hn;
      }
      // layer2 epilogue: h2[i-1] (skip at i==0; its MFMA inputs were zeros)
      if (i > 0) {
#pragma unroll
        for (int r = 0; r < 4; ++r) {
          float rg = sigm(cr[r]);
          float zg = sigm(cz[r]);
          float ng = tanh_fast(fmaf(rg, chn[r], cin[r]));
          float hn = fmaf(zg, h2p[r] - ng, ng);
          h2p[r] = hn;
          h2b[wb][q * 4 + r][jc] = (half_t)hn;
        }
      }
      __syncthreads();
    }
  }

  // final layer2 step 127: h1[127] & h2[126] live in parity-0 buffers (i=128)
  {
    f32x4 cr  = {b2r, b2r, b2r, b2r};
    f32x4 cz  = {b2z, b2z, b2z, b2z};
    f32x4 cin = {b2in, b2in, b2in, b2in};
    f32x4 chn = {b2hn, b2hn, b2hn, b2hn};
#pragma unroll
    for (int kk = 0; kk < 4; ++kk) {
      half8 a1 = *(const half8*)&h1b[0][c][kk * 32 + q * 8];
      half8 a2 = *(const half8*)&h2b[0][c][kk * 32 + q * 8];
      cr  = mfma16(a1, wi2r[kk], cr);
      cz  = mfma16(a1, wi2z[kk], cz);
      cin = mfma16(a1, wi2n[kk], cin);
      cr  = mfma16(a2, wh2r[kk], cr);
      cz  = mfma16(a2, wh2z[kk], cz);
      chn = mfma16(a2, wh2n[kk], chn);
    }
#pragma unroll
    for (int r = 0; r < 4; ++r) {
      float rg = sigm(cr[r]);
      float zg = sigm(cz[r]);
      float ng = tanh_fast(fmaf(rg, chn[r], cin[r]));
      h2p[r] = fmaf(zg, h2p[r] - ng, ng);
    }
  }

  // ---------------- FC epilogue (pure fp32) ----------------
#pragma unroll
  for (int r = 0; r < 4; ++r) h2f[q * 4 + r][jc] = h2p[r];
  __syncthreads();
  if (tid < 384) {
    const int m = tid & 15;
    const int cls = tid >> 4;  // 0..23
    const float* w = fcw + cls * 128;
    float acc = fcb[cls];
#pragma unroll 8
    for (int j = 0; j < 128; ++j) acc = fmaf(h2f[m][j], w[j], acc);
    out[(size_t)(s0 + m) * 24 + cls] = acc;
  }
}

extern "C" void kernel_launch(void* const* d_in, const int* in_sizes, int n_in,
                              void* d_out, int out_size, void* d_ws, size_t ws_size,
                              hipStream_t stream) {
  (void)in_sizes; (void)n_in; (void)d_ws; (void)ws_size; (void)out_size;
  const float* x    = (const float*)d_in[0];
  const float* wih1 = (const float*)d_in[1];
  const float* whh1 = (const float*)d_in[2];
  const float* bih1 = (const float*)d_in[3];
  const float* bhh1 = (const float*)d_in[4];
  const float* wih2 = (const float*)d_in[5];
  const float* whh2 = (const float*)d_in[6];
  const float* bih2 = (const float*)d_in[7];
  const float* bhh2 = (const float*)d_in[8];
  const float* fcw  = (const float*)d_in[9];
  const float* fcb  = (const float*)d_in[10];
  float* outp = (float*)d_out;
  gru_fused<<<dim3(256), dim3(512), 0, stream>>>(
      x, wih1, whh1, bih1, bhh1, wih2, whh2, bih2, bhh2, fcw, fcb, outp);
}

// Round 5
// 352.013 us; speedup vs baseline: 1.2769x; 1.2769x over previous
//
#include <hip/hip_runtime.h>

// Fused 2-layer GRU + FC for (B=4096, L=128, IN=16, H=128, NC=24).
// 256 blocks x 256 threads, __launch_bounds__(256,1): 4 waves/CU, ONE wave per
// SIMD => 512 unified regs/wave (256 arch + 256 AGPR). Each wave owns 32
// h-columns (2 MFMA col-tiles). Weight fragments (78 x 4 = 312 regs) live in
// the register file; they are only consumed as MFMA B-operands, which read
// AGPR directly on gfx950, so the allocator can park them in the acc file.
// Rounds 1-4 showed any 512-thread layout (256-reg cap) spills ~30KB/block of
// weights to scratch and reloads them every timestep. No pin hacks here.
// Layer2 runs one step behind layer1: single barrier per step, 78 independent
// MFMAs of ILP per barrier interval per wave.

typedef _Float16 half_t;
typedef _Float16 half8 __attribute__((ext_vector_type(8)));
typedef _Float16 half4v __attribute__((ext_vector_type(4)));
typedef float f32x4 __attribute__((ext_vector_type(4)));

#define BB 16      // batch rows per block
#define HS 136     // h row stride (halves)
#define XS 520     // x chunk row stride (halves): 32*16 + 8 pad

static __device__ __forceinline__ f32x4 mfma16(half8 a, half8 b, f32x4 c) {
  return __builtin_amdgcn_mfma_f32_16x16x32_f16(a, b, c, 0, 0, 0);
}

static __device__ __forceinline__ half8 zero8() {
  half8 v;
#pragma unroll
  for (int i = 0; i < 8; ++i) v[i] = (half_t)0.f;
  return v;
}

static __device__ __forceinline__ half8 ldw8(const float* __restrict__ p) {
  float4 a = *(const float4*)p;
  float4 b = *(const float4*)(p + 4);
  half8 r;
  r[0] = (half_t)a.x; r[1] = (half_t)a.y; r[2] = (half_t)a.z; r[3] = (half_t)a.w;
  r[4] = (half_t)b.x; r[5] = (half_t)b.y; r[6] = (half_t)b.z; r[7] = (half_t)b.w;
  return r;
}

static __device__ __forceinline__ float sigm(float v) {
  return __builtin_amdgcn_rcpf(1.f + __expf(-v));
}
static __device__ __forceinline__ float tanh_fast(float v) {
  float e = __expf(2.f * v);
  return 1.f - 2.f * __builtin_amdgcn_rcpf(1.f + e);
}

__global__ __launch_bounds__(256, 1) void gru_fused(
    const float* __restrict__ x,                                    // (4096,2,1024)
    const float* __restrict__ wih1, const float* __restrict__ whh1, // (384,16),(384,128)
    const float* __restrict__ bih1, const float* __restrict__ bhh1,
    const float* __restrict__ wih2, const float* __restrict__ whh2, // (384,128)x2
    const float* __restrict__ bih2, const float* __restrict__ bhh2,
    const float* __restrict__ fcw, const float* __restrict__ fcb,   // (24,128),(24,)
    float* __restrict__ out)                                        // (4096,24)
{
  __shared__ __align__(16) half_t xl[BB][XS];        // 16640 B
  __shared__ __align__(16) half_t h1b[2][BB][HS];    //  8704 B
  __shared__ __align__(16) half_t h2b[2][BB][HS];    //  8704 B
  __shared__ float h2f[BB][129];                     //  8256 B

  const int tid = threadIdx.x;
  const int lane = tid & 63;
  const int wv = tid >> 6;      // wave 0..3
  const int q = lane >> 4;      // quad 0..3
  const int c = lane & 15;
  const int jc0 = wv * 32 + c;  // col-tile 0 column
  const int jc1 = jc0 + 16;     // col-tile 1 column
  const int s0 = blockIdx.x * BB;

  // zero both parity buffers of both states (layer2 MFMAs run unguarded at i=0)
  for (int i = tid; i < 2 * BB * HS; i += 256) {
    ((half_t*)h1b)[i] = (half_t)0.f;
    ((half_t*)h2b)[i] = (half_t)0.f;
  }

  // biases per col-tile (r/z fold b_ih+b_hh; n split for r*(Wh+b_hh) semantics)
  float b1r[2], b1z[2], b1in[2], b1hn[2], b2r[2], b2z[2], b2in[2], b2hn[2];
#pragma unroll
  for (int tl = 0; tl < 2; ++tl) {
    const int jc = jc0 + tl * 16;
    b1r[tl]  = bih1[jc]       + bhh1[jc];
    b1z[tl]  = bih1[128 + jc] + bhh1[128 + jc];
    b1in[tl] = bih1[256 + jc];
    b1hn[tl] = bhh1[256 + jc];
    b2r[tl]  = bih2[jc]       + bhh2[jc];
    b2z[tl]  = bih2[128 + jc] + bhh2[128 + jc];
    b2in[tl] = bih2[256 + jc];
    b2hn[tl] = bhh2[256 + jc];
  }

  // weight B-fragments: lane holds W[n=jc][k = kk*32 + q*8 + j]
  half8 wi1r[2], wi1z[2], wi1n[2];
  half8 wh1r[2][4], wh1z[2][4], wh1n[2][4];
  half8 wi2r[2][4], wi2z[2][4], wi2n[2][4];
  half8 wh2r[2][4], wh2z[2][4], wh2n[2][4];
#pragma unroll
  for (int tl = 0; tl < 2; ++tl) {
    const int jc = jc0 + tl * 16;
    if (q < 2) {  // real K=16, quads 2..3 are zero-pad
      wi1r[tl] = ldw8(wih1 + (0 * 128 + jc) * 16 + q * 8);
      wi1z[tl] = ldw8(wih1 + (1 * 128 + jc) * 16 + q * 8);
      wi1n[tl] = ldw8(wih1 + (2 * 128 + jc) * 16 + q * 8);
    } else {
      wi1r[tl] = zero8(); wi1z[tl] = zero8(); wi1n[tl] = zero8();
    }
#pragma unroll
    for (int kk = 0; kk < 4; ++kk) {
      const int ko = kk * 32 + q * 8;
      wh1r[tl][kk] = ldw8(whh1 + (0 * 128 + jc) * 128 + ko);
      wh1z[tl][kk] = ldw8(whh1 + (1 * 128 + jc) * 128 + ko);
      wh1n[tl][kk] = ldw8(whh1 + (2 * 128 + jc) * 128 + ko);
      wi2r[tl][kk] = ldw8(wih2 + (0 * 128 + jc) * 128 + ko);
      wi2z[tl][kk] = ldw8(wih2 + (1 * 128 + jc) * 128 + ko);
      wi2n[tl][kk] = ldw8(wih2 + (2 * 128 + jc) * 128 + ko);
      wh2r[tl][kk] = ldw8(whh2 + (0 * 128 + jc) * 128 + ko);
      wh2z[tl][kk] = ldw8(whh2 + (1 * 128 + jc) * 128 + ko);
      wh2n[tl][kk] = ldw8(whh2 + (2 * 128 + jc) * 128 + ko);
    }
  }

  // fp32 hidden state, lane-resident: rows m = 4q+r, cols jc0/jc1
  float h1p[2][4] = {{0.f, 0.f, 0.f, 0.f}, {0.f, 0.f, 0.f, 0.f}};
  float h2p[2][4] = {{0.f, 0.f, 0.f, 0.f}, {0.f, 0.f, 0.f, 0.f}};

  for (int tc = 0; tc < 4; ++tc) {
    // stage x[s][ch][tc*256 .. +255] -> xl[s][tl*16 + ch*8 + k], fp16
#pragma unroll
    for (int it = 0; it < 8; ++it) {
      int idx = tid + it * 256;         // 0..2047 float4s
      int s = idx >> 7;
      int rem = idx & 127;
      int ch = rem >> 6;
      int i4 = rem & 63;
      const float4 v = *(const float4*)(x + (size_t)(s0 + s) * 2048 + ch * 1024 + tc * 256 + i4 * 4);
      half4v hv;
      hv[0] = (half_t)v.x; hv[1] = (half_t)v.y; hv[2] = (half_t)v.z; hv[3] = (half_t)v.w;
      *(half4v*)&xl[s][(i4 >> 1) * 16 + ch * 8 + (i4 & 1) * 4] = hv;
    }
    __syncthreads();

    for (int tt = 0; tt < 32; ++tt) {
      const int i = tc * 32 + tt;      // layer1 step index; layer2 does step i-1
      const int rb = i & 1;
      const int wb = rb ^ 1;

      f32x4 ar[2], az[2], ain[2], ahn[2], cr[2], cz[2], cin[2], chn[2];
#pragma unroll
      for (int tl = 0; tl < 2; ++tl) {
        ar[tl]  = (f32x4){b1r[tl], b1r[tl], b1r[tl], b1r[tl]};
        az[tl]  = (f32x4){b1z[tl], b1z[tl], b1z[tl], b1z[tl]};
        ain[tl] = (f32x4){b1in[tl], b1in[tl], b1in[tl], b1in[tl]};
        ahn[tl] = (f32x4){b1hn[tl], b1hn[tl], b1hn[tl], b1hn[tl]};
        cr[tl]  = (f32x4){b2r[tl], b2r[tl], b2r[tl], b2r[tl]};
        cz[tl]  = (f32x4){b2z[tl], b2z[tl], b2z[tl], b2z[tl]};
        cin[tl] = (f32x4){b2in[tl], b2in[tl], b2in[tl], b2in[tl]};
        chn[tl] = (f32x4){b2hn[tl], b2hn[tl], b2hn[tl], b2hn[tl]};
      }

      {
        half8 ax = zero8();
        if (q < 2) ax = *(const half8*)&xl[c][tt * 16 + q * 8];
#pragma unroll
        for (int tl = 0; tl < 2; ++tl) {
          ar[tl]  = mfma16(ax, wi1r[tl], ar[tl]);
          az[tl]  = mfma16(ax, wi1z[tl], az[tl]);
          ain[tl] = mfma16(ax, wi1n[tl], ain[tl]);
        }
      }
#pragma unroll
      for (int kk = 0; kk < 4; ++kk) {
        half8 ah = *(const half8*)&h1b[rb][c][kk * 32 + q * 8];  // h1[i-1]
        half8 a2 = *(const half8*)&h2b[rb][c][kk * 32 + q * 8];  // h2[i-2]
#pragma unroll
        for (int tl = 0; tl < 2; ++tl) {
          ar[tl]  = mfma16(ah, wh1r[tl][kk], ar[tl]);
          az[tl]  = mfma16(ah, wh1z[tl][kk], az[tl]);
          ahn[tl] = mfma16(ah, wh1n[tl][kk], ahn[tl]);
          cr[tl]  = mfma16(ah, wi2r[tl][kk], cr[tl]);   // layer2 input = h1[i-1]
          cz[tl]  = mfma16(ah, wi2z[tl][kk], cz[tl]);
          cin[tl] = mfma16(ah, wi2n[tl][kk], cin[tl]);
          cr[tl]  = mfma16(a2, wh2r[tl][kk], cr[tl]);
          cz[tl]  = mfma16(a2, wh2z[tl][kk], cz[tl]);
          chn[tl] = mfma16(a2, wh2n[tl][kk], chn[tl]);
        }
      }

      // layer1 epilogue: h1[i]
#pragma unroll
      for (int tl = 0; tl < 2; ++tl) {
        const int jc = (tl == 0) ? jc0 : jc1;
#pragma unroll
        for (int r = 0; r < 4; ++r) {
          float rg = sigm(ar[tl][r]);
          float zg = sigm(az[tl][r]);
          float ng = tanh_fast(fmaf(rg, ahn[tl][r], ain[tl][r]));
          float hn = fmaf(zg, h1p[tl][r] - ng, ng);   // (1-z)*n + z*h
          h1p[tl][r] = hn;
          h1b[wb][q * 4 + r][jc] = (half_t)hn;
        }
      }
      // layer2 epilogue: h2[i-1] (skip at i==0; its MFMA inputs were zeros)
      if (i > 0) {
#pragma unroll
        for (int tl = 0; tl < 2; ++tl) {
          const int jc = (tl == 0) ? jc0 : jc1;
#pragma unroll
          for (int r = 0; r < 4; ++r) {
            float rg = sigm(cr[tl][r]);
            float zg = sigm(cz[tl][r]);
            float ng = tanh_fast(fmaf(rg, chn[tl][r], cin[tl][r]));
            float hn = fmaf(zg, h2p[tl][r] - ng, ng);
            h2p[tl][r] = hn;
            h2b[wb][q * 4 + r][jc] = (half_t)hn;
          }
        }
      }
      __syncthreads();
    }
  }

  // final layer2 step 127: h1[127] & h2[126] live in parity-0 buffers (i=128)
  {
    f32x4 cr[2], cz[2], cin[2], chn[2];
#pragma unroll
    for (int tl = 0; tl < 2; ++tl) {
      cr[tl]  = (f32x4){b2r[tl], b2r[tl], b2r[tl], b2r[tl]};
      cz[tl]  = (f32x4){b2z[tl], b2z[tl], b2z[tl], b2z[tl]};
      cin[tl] = (f32x4){b2in[tl], b2in[tl], b2in[tl], b2in[tl]};
      chn[tl] = (f32x4){b2hn[tl], b2hn[tl], b2hn[tl], b2hn[tl]};
    }
#pragma unroll
    for (int kk = 0; kk < 4; ++kk) {
      half8 a1 = *(const half8*)&h1b[0][c][kk * 32 + q * 8];
      half8 a2 = *(const half8*)&h2b[0][c][kk * 32 + q * 8];
#pragma unroll
      for (int tl = 0; tl < 2; ++tl) {
        cr[tl]  = mfma16(a1, wi2r[tl][kk], cr[tl]);
        cz[tl]  = mfma16(a1, wi2z[tl][kk], cz[tl]);
        cin[tl] = mfma16(a1, wi2n[tl][kk], cin[tl]);
        cr[tl]  = mfma16(a2, wh2r[tl][kk], cr[tl]);
        cz[tl]  = mfma16(a2, wh2z[tl][kk], cz[tl]);
        chn[tl] = mfma16(a2, wh2n[tl][kk], chn[tl]);
      }
    }
#pragma unroll
    for (int tl = 0; tl < 2; ++tl) {
#pragma unroll
      for (int r = 0; r < 4; ++r) {
        float rg = sigm(cr[tl][r]);
        float zg = sigm(cz[tl][r]);
        float ng = tanh_fast(fmaf(rg, chn[tl][r], cin[tl][r]));
        h2p[tl][r] = fmaf(zg, h2p[tl][r] - ng, ng);
      }
    }
  }

  // ---------------- FC epilogue (pure fp32) ----------------
#pragma unroll
  for (int tl = 0; tl < 2; ++tl) {
    const int jc = (tl == 0) ? jc0 : jc1;
#pragma unroll
    for (int r = 0; r < 4; ++r) h2f[q * 4 + r][jc] = h2p[tl][r];
  }
  __syncthreads();
  for (int job = tid; job < 384; job += 256) {
    const int m = job & 15;
    const int cls = job >> 4;  // 0..23
    const float* w = fcw + cls * 128;
    float acc = fcb[cls];
#pragma unroll 8
    for (int j = 0; j < 128; ++j) acc = fmaf(h2f[m][j], w[j], acc);
    out[(size_t)(s0 + m) * 24 + cls] = acc;
  }
}

extern "C" void kernel_launch(void* const* d_in, const int* in_sizes, int n_in,
                              void* d_out, int out_size, void* d_ws, size_t ws_size,
                              hipStream_t stream) {
  (void)in_sizes; (void)n_in; (void)d_ws; (void)ws_size; (void)out_size;
  const float* x    = (const float*)d_in[0];
  const float* wih1 = (const float*)d_in[1];
  const float* whh1 = (const float*)d_in[2];
  const float* bih1 = (const float*)d_in[3];
  const float* bhh1 = (const float*)d_in[4];
  const float* wih2 = (const float*)d_in[5];
  const float* whh2 = (const float*)d_in[6];
  const float* bih2 = (const float*)d_in[7];
  const float* bhh2 = (const float*)d_in[8];
  const float* fcw  = (const float*)d_in[9];
  const float* fcb  = (const float*)d_in[10];
  float* outp = (float*)d_out;
  gru_fused<<<dim3(256), dim3(256), 0, stream>>>(
      x, wih1, whh1, bih1, bhh1, wih2, whh2, bih2, bhh2, fcw, fcb, outp);
}

// Round 6
// 295.936 us; speedup vs baseline: 1.5188x; 1.1895x over previous
//
#include <hip/hip_runtime.h>

// Fused 2-layer GRU + FC for (B=4096, L=128, IN=16, H=128, NC=24), split into
// TWO kernels to halve register pressure (rounds 1-5: compiler refuses to keep
// the full 156-reg/wave weight set live; remats ~290KB/step from L1/L2 at any
// occupancy). Layer coupling seq1 = h1 sequence (4096x128x128 fp16 = 128 MiB)
// goes through d_ws. K1: 60 weight regs/wave. K2: 96 weight regs/wave. Both
// 256 blocks x 512 thr (8 waves, 16 cols/wave, 16 batch rows/block, 2 w/SIMD).
// Fallback single fused kernel (round-3 version, 229 us) if ws too small.

typedef _Float16 half_t;
typedef _Float16 half8 __attribute__((ext_vector_type(8)));
typedef _Float16 half4v __attribute__((ext_vector_type(4)));
typedef float f32x4 __attribute__((ext_vector_type(4)));

#define BB 16      // batch rows per block
#define HS 136     // padded row stride (halves): +16B -> 2-way-max LDS banks
#define XS 520     // x chunk row stride (halves)

static __device__ __forceinline__ f32x4 mfma16(half8 a, half8 b, f32x4 c) {
  return __builtin_amdgcn_mfma_f32_16x16x32_f16(a, b, c, 0, 0, 0);
}

static __device__ __forceinline__ half8 zero8() {
  half8 v;
#pragma unroll
  for (int i = 0; i < 8; ++i) v[i] = (half_t)0.f;
  return v;
}

static __device__ __forceinline__ half8 ldw8(const float* __restrict__ p) {
  float4 a = *(const float4*)p;
  float4 b = *(const float4*)(p + 4);
  half8 r;
  r[0] = (half_t)a.x; r[1] = (half_t)a.y; r[2] = (half_t)a.z; r[3] = (half_t)a.w;
  r[4] = (half_t)b.x; r[5] = (half_t)b.y; r[6] = (half_t)b.z; r[7] = (half_t)b.w;
  return r;
}

static __device__ __forceinline__ float sigm(float v) {
  return __builtin_amdgcn_rcpf(1.f + __expf(-v));
}
static __device__ __forceinline__ float tanh_fast(float v) {
  float e = __expf(2.f * v);
  return 1.f - 2.f * __builtin_amdgcn_rcpf(1.f + e);
}

// ============================ Kernel 1: layer 1 ============================
// h1 ring (8 steps) in LDS doubles as recurrence buffer; flushed to seq1
// (layout [b][t][c], fp16) every 8 steps as coalesced 16B stores.
__global__ __launch_bounds__(512, 2) void gru_l1(
    const float* __restrict__ x,                                    // (4096,2,1024)
    const float* __restrict__ wih1, const float* __restrict__ whh1, // (384,16),(384,128)
    const float* __restrict__ bih1, const float* __restrict__ bhh1,
    half_t* __restrict__ seq1)                                      // (4096,128,128) fp16
{
  __shared__ __align__(16) half_t xl[BB][XS];        // 16640 B
  __shared__ __align__(16) half_t ost[8][BB][HS];    // 34816 B, slot i&7 = h1[i]

  const int tid = threadIdx.x;
  const int lane = tid & 63;
  const int wv = tid >> 6;
  const int q = lane >> 4;
  const int c = lane & 15;
  const int jc = wv * 16 + c;
  const int s0 = blockIdx.x * BB;

  for (int i = tid; i < 8 * BB * HS; i += 512) ((half_t*)ost)[i] = (half_t)0.f;

  const float b1r  = bih1[jc]       + bhh1[jc];
  const float b1z  = bih1[128 + jc] + bhh1[128 + jc];
  const float b1in = bih1[256 + jc];
  const float b1hn = bhh1[256 + jc];

  half8 wi1r, wi1z, wi1n;
  if (q < 2) {
    wi1r = ldw8(wih1 + (0 * 128 + jc) * 16 + q * 8);
    wi1z = ldw8(wih1 + (1 * 128 + jc) * 16 + q * 8);
    wi1n = ldw8(wih1 + (2 * 128 + jc) * 16 + q * 8);
  } else {
    wi1r = zero8(); wi1z = zero8(); wi1n = zero8();
  }
  half8 wh1r[4], wh1z[4], wh1n[4];
#pragma unroll
  for (int kk = 0; kk < 4; ++kk) {
    const int ko = kk * 32 + q * 8;
    wh1r[kk] = ldw8(whh1 + (0 * 128 + jc) * 128 + ko);
    wh1z[kk] = ldw8(whh1 + (1 * 128 + jc) * 128 + ko);
    wh1n[kk] = ldw8(whh1 + (2 * 128 + jc) * 128 + ko);
  }

  float h1p[4] = {0.f, 0.f, 0.f, 0.f};

  for (int g = 0; g < 16; ++g) {          // 8-step groups
    if ((g & 3) == 0) {
      const int tc = g >> 2;              // 32-step x chunk
#pragma unroll
      for (int it = 0; it < 4; ++it) {
        int idx = tid + it * 512;
        int s = idx >> 7;
        int rem = idx & 127;
        int ch = rem >> 6;
        int i4 = rem & 63;
        const float4 v = *(const float4*)(x + (size_t)(s0 + s) * 2048 + ch * 1024 + tc * 256 + i4 * 4);
        half4v hv;
        hv[0] = (half_t)v.x; hv[1] = (half_t)v.y; hv[2] = (half_t)v.z; hv[3] = (half_t)v.w;
        *(half4v*)&xl[s][(i4 >> 1) * 16 + ch * 8 + (i4 & 1) * 4] = hv;
      }
      __syncthreads();
    }

    for (int tt = 0; tt < 8; ++tt) {
      const int i = g * 8 + tt;
      const int prev = (i + 7) & 7;

      f32x4 ar  = {b1r, b1r, b1r, b1r};
      f32x4 az  = {b1z, b1z, b1z, b1z};
      f32x4 ain = {b1in, b1in, b1in, b1in};
      f32x4 ahn = {b1hn, b1hn, b1hn, b1hn};
      {
        half8 ax = zero8();
        if (q < 2) ax = *(const half8*)&xl[c][(i & 31) * 16 + q * 8];
        ar  = mfma16(ax, wi1r, ar);
        az  = mfma16(ax, wi1z, az);
        ain = mfma16(ax, wi1n, ain);
      }
#pragma unroll
      for (int kk = 0; kk < 4; ++kk) {
        half8 ah = *(const half8*)&ost[prev][c][kk * 32 + q * 8];   // h1[i-1]
        ar  = mfma16(ah, wh1r[kk], ar);
        az  = mfma16(ah, wh1z[kk], az);
        ahn = mfma16(ah, wh1n[kk], ahn);
      }
#pragma unroll
      for (int r = 0; r < 4; ++r) {
        float rg = sigm(ar[r]);
        float zg = sigm(az[r]);
        float ng = tanh_fast(fmaf(rg, ahn[r], ain[r]));
        float hn = fmaf(zg, h1p[r] - ng, ng);   // (1-z)*n + z*h
        h1p[r] = hn;
        ost[tt][q * 4 + r][jc] = (half_t)hn;
      }
      __syncthreads();  // h1[i] visible to all waves
    }

    // flush group g (steps g*8 .. g*8+7) to seq1, coalesced 16B units
#pragma unroll
    for (int p = 0; p < 4; ++p) {
      int idx = tid + p * 512;            // 0..2047
      int col16 = idx & 15;
      int row = (idx >> 4) & 15;
      int st = idx >> 8;                  // 0..7
      f32x4 v = *(const f32x4*)&ost[st][row][col16 * 8];
      size_t off = ((size_t)((s0 + row) * 128 + (g * 8 + st))) * 128 + col16 * 8;
      *(f32x4*)(seq1 + off) = v;
    }
    __syncthreads();  // flush reads done before next group's ring overwrite
  }
}

// ============================ Kernel 2: layer 2 + FC =======================
// seq1 streamed in 8-step chunks, double-buffered LDS, register prefetch
// one chunk ahead (no load stall).
__global__ __launch_bounds__(512, 2) void gru_l2(
    const half_t* __restrict__ seq1,                                // (4096,128,128) fp16
    const float* __restrict__ wih2, const float* __restrict__ whh2, // (384,128)x2
    const float* __restrict__ bih2, const float* __restrict__ bhh2,
    const float* __restrict__ fcw, const float* __restrict__ fcb,   // (24,128),(24,)
    float* __restrict__ out)                                        // (4096,24)
{
  __shared__ __align__(16) half_t sc[2][8][BB][HS];  // 69632 B
  __shared__ __align__(16) half_t h2b[2][BB][HS];    //  8704 B
  __shared__ float h2f[BB][129];                     //  8256 B

  const int tid = threadIdx.x;
  const int lane = tid & 63;
  const int wv = tid >> 6;
  const int q = lane >> 4;
  const int c = lane & 15;
  const int jc = wv * 16 + c;
  const int s0 = blockIdx.x * BB;

  for (int i = tid; i < BB * HS; i += 512) ((half_t*)h2b[0])[i] = (half_t)0.f;

  const float b2r  = bih2[jc]       + bhh2[jc];
  const float b2z  = bih2[128 + jc] + bhh2[128 + jc];
  const float b2in = bih2[256 + jc];
  const float b2hn = bhh2[256 + jc];

  half8 wi2r[4], wi2z[4], wi2n[4], wh2r[4], wh2z[4], wh2n[4];
#pragma unroll
  for (int kk = 0; kk < 4; ++kk) {
    const int ko = kk * 32 + q * 8;
    wi2r[kk] = ldw8(wih2 + (0 * 128 + jc) * 128 + ko);
    wi2z[kk] = ldw8(wih2 + (1 * 128 + jc) * 128 + ko);
    wi2n[kk] = ldw8(wih2 + (2 * 128 + jc) * 128 + ko);
    wh2r[kk] = ldw8(whh2 + (0 * 128 + jc) * 128 + ko);
    wh2z[kk] = ldw8(whh2 + (1 * 128 + jc) * 128 + ko);
    wh2n[kk] = ldw8(whh2 + (2 * 128 + jc) * 128 + ko);
  }

  // preload chunk 0 into sc[0]
#pragma unroll
  for (int p = 0; p < 4; ++p) {
    int idx = tid + p * 512;
    int col16 = idx & 15;
    int row = (idx >> 4) & 15;
    int st = idx >> 8;
    size_t off = ((size_t)((s0 + row) * 128 + st)) * 128 + col16 * 8;
    *(f32x4*)&sc[0][st][row][col16 * 8] = *(const f32x4*)(seq1 + off);
  }
  __syncthreads();

  float h2p[4] = {0.f, 0.f, 0.f, 0.f};

  for (int ch = 0; ch < 16; ++ch) {
    f32x4 pf[4];
    if (ch < 15) {
#pragma unroll
      for (int p = 0; p < 4; ++p) {       // prefetch chunk ch+1 into regs
        int idx = tid + p * 512;
        int col16 = idx & 15;
        int row = (idx >> 4) & 15;
        int st = idx >> 8;
        size_t off = ((size_t)((s0 + row) * 128 + ((ch + 1) * 8 + st))) * 128 + col16 * 8;
        pf[p] = *(const f32x4*)(seq1 + off);
      }
    }
    const int cb = ch & 1;

    for (int tt = 0; tt < 8; ++tt) {
      const int i = ch * 8 + tt;
      const int rb = i & 1;
      const int wb = rb ^ 1;

      f32x4 cr  = {b2r, b2r, b2r, b2r};
      f32x4 cz  = {b2z, b2z, b2z, b2z};
      f32x4 cin = {b2in, b2in, b2in, b2in};
      f32x4 chn = {b2hn, b2hn, b2hn, b2hn};
#pragma unroll
      for (int kk = 0; kk < 4; ++kk) {
        half8 a1 = *(const half8*)&sc[cb][tt][c][kk * 32 + q * 8];  // h1[i]
        half8 a2 = *(const half8*)&h2b[rb][c][kk * 32 + q * 8];     // h2[i-1]
        cr  = mfma16(a1, wi2r[kk], cr);
        cz  = mfma16(a1, wi2z[kk], cz);
        cin = mfma16(a1, wi2n[kk], cin);
        cr  = mfma16(a2, wh2r[kk], cr);
        cz  = mfma16(a2, wh2z[kk], cz);
        chn = mfma16(a2, wh2n[kk], chn);
      }
#pragma unroll
      for (int r = 0; r < 4; ++r) {
        float rg = sigm(cr[r]);
        float zg = sigm(cz[r]);
        float ng = tanh_fast(fmaf(rg, chn[r], cin[r]));
        float hn = fmaf(zg, h2p[r] - ng, ng);
        h2p[r] = hn;
        h2b[wb][q * 4 + r][jc] = (half_t)hn;
      }
      if (tt == 7 && ch < 15) {           // commit prefetched chunk to back buffer
#pragma unroll
        for (int p = 0; p < 4; ++p) {
          int idx = tid + p * 512;
          int col16 = idx & 15;
          int row = (idx >> 4) & 15;
          int st = idx >> 8;
          *(f32x4*)&sc[cb ^ 1][st][row][col16 * 8] = pf[p];
        }
      }
      __syncthreads();
    }
  }

  // FC epilogue (pure fp32)
#pragma unroll
  for (int r = 0; r < 4; ++r) h2f[q * 4 + r][jc] = h2p[r];
  __syncthreads();
  if (tid < 384) {
    const int m = tid & 15;
    const int cls = tid >> 4;
    const float* w = fcw + cls * 128;
    float acc = fcb[cls];
#pragma unroll 8
    for (int j = 0; j < 128; ++j) acc = fmaf(h2f[m][j], w[j], acc);
    out[(size_t)(s0 + m) * 24 + cls] = acc;
  }
}

// ===================== Fallback: round-3 fused kernel ======================
__global__ __launch_bounds__(512, 2) void gru_fused(
    const float* __restrict__ x,
    const float* __restrict__ wih1, const float* __restrict__ whh1,
    const float* __restrict__ bih1, const float* __restrict__ bhh1,
    const float* __restrict__ wih2, const float* __restrict__ whh2,
    const float* __restrict__ bih2, const float* __restrict__ bhh2,
    const float* __restrict__ fcw, const float* __restrict__ fcb,
    float* __restrict__ out)
{
  __shared__ __align__(16) half_t xl[BB][XS];
  __shared__ __align__(16) half_t h1b[2][BB][HS];
  __shared__ __align__(16) half_t h2b[2][BB][HS];
  __shared__ float h2f[BB][129];

  const int tid = threadIdx.x;
  const int lane = tid & 63;
  const int wv = tid >> 6;
  const int q = lane >> 4;
  const int c = lane & 15;
  const int jc = wv * 16 + c;
  const int s0 = blockIdx.x * BB;

  for (int i = tid; i < 2 * BB * HS; i += 512) {
    ((half_t*)h1b)[i] = (half_t)0.f;
    ((half_t*)h2b)[i] = (half_t)0.f;
  }

  const float b1r  = bih1[jc]       + bhh1[jc];
  const float b1z  = bih1[128 + jc] + bhh1[128 + jc];
  const float b1in = bih1[256 + jc];
  const float b1hn = bhh1[256 + jc];
  const float b2r  = bih2[jc]       + bhh2[jc];
  const float b2z  = bih2[128 + jc] + bhh2[128 + jc];
  const float b2in = bih2[256 + jc];
  const float b2hn = bhh2[256 + jc];

  half8 wi1r, wi1z, wi1n;
  if (q < 2) {
    wi1r = ldw8(wih1 + (0 * 128 + jc) * 16 + q * 8);
    wi1z = ldw8(wih1 + (1 * 128 + jc) * 16 + q * 8);
    wi1n = ldw8(wih1 + (2 * 128 + jc) * 16 + q * 8);
  } else {
    wi1r = zero8(); wi1z = zero8(); wi1n = zero8();
  }
  half8 wh1r[4], wh1z[4], wh1n[4], wi2r[4], wi2z[4], wi2n[4], wh2r[4], wh2z[4], wh2n[4];
#pragma unroll
  for (int kk = 0; kk < 4; ++kk) {
    const int ko = kk * 32 + q * 8;
    wh1r[kk] = ldw8(whh1 + (0 * 128 + jc) * 128 + ko);
    wh1z[kk] = ldw8(whh1 + (1 * 128 + jc) * 128 + ko);
    wh1n[kk] = ldw8(whh1 + (2 * 128 + jc) * 128 + ko);
    wi2r[kk] = ldw8(wih2 + (0 * 128 + jc) * 128 + ko);
    wi2z[kk] = ldw8(wih2 + (1 * 128 + jc) * 128 + ko);
    wi2n[kk] = ldw8(wih2 + (2 * 128 + jc) * 128 + ko);
    wh2r[kk] = ldw8(whh2 + (0 * 128 + jc) * 128 + ko);
    wh2z[kk] = ldw8(whh2 + (1 * 128 + jc) * 128 + ko);
    wh2n[kk] = ldw8(whh2 + (2 * 128 + jc) * 128 + ko);
  }

  float h1p[4] = {0.f, 0.f, 0.f, 0.f};
  float h2p[4] = {0.f, 0.f, 0.f, 0.f};

  for (int tc = 0; tc < 4; ++tc) {
#pragma unroll
    for (int it = 0; it < 4; ++it) {
      int idx = tid + it * 512;
      int s = idx >> 7;
      int rem = idx & 127;
      int ch = rem >> 6;
      int i4 = rem & 63;
      const float4 v = *(const float4*)(x + (size_t)(s0 + s) * 2048 + ch * 1024 + tc * 256 + i4 * 4);
      half4v hv;
      hv[0] = (half_t)v.x; hv[1] = (half_t)v.y; hv[2] = (half_t)v.z; hv[3] = (half_t)v.w;
      *(half4v*)&xl[s][(i4 >> 1) * 16 + ch * 8 + (i4 & 1) * 4] = hv;
    }
    __syncthreads();

    for (int tt = 0; tt < 32; ++tt) {
      const int i = tc * 32 + tt;
      const int rb = i & 1;
      const int wb = rb ^ 1;

      f32x4 ar  = {b1r, b1r, b1r, b1r};
      f32x4 az  = {b1z, b1z, b1z, b1z};
      f32x4 ain = {b1in, b1in, b1in, b1in};
      f32x4 ahn = {b1hn, b1hn, b1hn, b1hn};
      f32x4 cr  = {b2r, b2r, b2r, b2r};
      f32x4 cz  = {b2z, b2z, b2z, b2z};
      f32x4 cin = {b2in, b2in, b2in, b2in};
      f32x4 chn = {b2hn, b2hn, b2hn, b2hn};

      {
        half8 ax = zero8();
        if (q < 2) ax = *(const half8*)&xl[c][tt * 16 + q * 8];
        ar  = mfma16(ax, wi1r, ar);
        az  = mfma16(ax, wi1z, az);
        ain = mfma16(ax, wi1n, ain);
      }
#pragma unroll
      for (int kk = 0; kk < 4; ++kk) {
        half8 ah = *(const half8*)&h1b[rb][c][kk * 32 + q * 8];
        half8 a2 = *(const half8*)&h2b[rb][c][kk * 32 + q * 8];
        ar  = mfma16(ah, wh1r[kk], ar);
        az  = mfma16(ah, wh1z[kk], az);
        ahn = mfma16(ah, wh1n[kk], ahn);
        cr  = mfma16(ah, wi2r[kk], cr);
        cz  = mfma16(ah, wi2z[kk], cz);
        cin = mfma16(ah, wi2n[kk], cin);
        cr  = mfma16(a2, wh2r[kk], cr);
        cz  = mfma16(a2, wh2z[kk], cz);
        chn = mfma16(a2, wh2n[kk], chn);
      }

#pragma unroll
      for (int r = 0; r < 4; ++r) {
        float rg = sigm(ar[r]);
        float zg = sigm(az[r]);
        float ng = tanh_fast(fmaf(rg, ahn[r], ain[r]));
        float hn = fmaf(zg, h1p[r] - ng, ng);
        h1p[r] = hn;
        h1b[wb][q * 4 + r][jc] = (half_t)hn;
      }
      if (i > 0) {
#pragma unroll
        for (int r = 0; r < 4; ++r) {
          float rg = sigm(cr[r]);
          float zg = sigm(cz[r]);
          float ng = tanh_fast(fmaf(rg, chn[r], cin[r]));
          float hn = fmaf(zg, h2p[r] - ng, ng);
          h2p[r] = hn;
          h2b[wb][q * 4 + r][jc] = (half_t)hn;
        }
      }
      __syncthreads();
    }
  }

  {
    f32x4 cr  = {b2r, b2r, b2r, b2r};
    f32x4 cz  = {b2z, b2z, b2z, b2z};
    f32x4 cin = {b2in, b2in, b2in, b2in};
    f32x4 chn = {b2hn, b2hn, b2hn, b2hn};
#pragma unroll
    for (int kk = 0; kk < 4; ++kk) {
      half8 a1 = *(const half8*)&h1b[0][c][kk * 32 + q * 8];
      half8 a2 = *(const half8*)&h2b[0][c][kk * 32 + q * 8];
      cr  = mfma16(a1, wi2r[kk], cr);
      cz  = mfma16(a1, wi2z[kk], cz);
      cin = mfma16(a1, wi2n[kk], cin);
      cr  = mfma16(a2, wh2r[kk], cr);
      cz  = mfma16(a2, wh2z[kk], cz);
      chn = mfma16(a2, wh2n[kk], chn);
    }
#pragma unroll
    for (int r = 0; r < 4; ++r) {
      float rg = sigm(cr[r]);
      float zg = sigm(cz[r]);
      float ng = tanh_fast(fmaf(rg, chn[r], cin[r]));
      h2p[r] = fmaf(zg, h2p[r] - ng, ng);
    }
  }

#pragma unroll
  for (int r = 0; r < 4; ++r) h2f[q * 4 + r][jc] = h2p[r];
  __syncthreads();
  if (tid < 384) {
    const int m = tid & 15;
    const int cls = tid >> 4;
    const float* w = fcw + cls * 128;
    float acc = fcb[cls];
#pragma unroll 8
    for (int j = 0; j < 128; ++j) acc = fmaf(h2f[m][j], w[j], acc);
    out[(size_t)(s0 + m) * 24 + cls] = acc;
  }
}

extern "C" void kernel_launch(void* const* d_in, const int* in_sizes, int n_in,
                              void* d_out, int out_size, void* d_ws, size_t ws_size,
                              hipStream_t stream) {
  (void)in_sizes; (void)n_in; (void)out_size;
  const float* x    = (const float*)d_in[0];
  const float* wih1 = (const float*)d_in[1];
  const float* whh1 = (const float*)d_in[2];
  const float* bih1 = (const float*)d_in[3];
  const float* bhh1 = (const float*)d_in[4];
  const float* wih2 = (const float*)d_in[5];
  const float* whh2 = (const float*)d_in[6];
  const float* bih2 = (const float*)d_in[7];
  const float* bhh2 = (const float*)d_in[8];
  const float* fcw  = (const float*)d_in[9];
  const float* fcb  = (const float*)d_in[10];
  float* outp = (float*)d_out;

  const size_t seq_bytes = (size_t)4096 * 128 * 128 * sizeof(half_t);  // 128 MiB
  if (ws_size >= seq_bytes) {
    half_t* seq1 = (half_t*)d_ws;
    gru_l1<<<dim3(256), dim3(512), 0, stream>>>(x, wih1, whh1, bih1, bhh1, seq1);
    gru_l2<<<dim3(256), dim3(512), 0, stream>>>(seq1, wih2, whh2, bih2, bhh2, fcw, fcb, outp);
  } else {
    gru_fused<<<dim3(256), dim3(512), 0, stream>>>(
        x, wih1, whh1, bih1, bhh1, wih2, whh2, bih2, bhh2, fcw, fcb, outp);
  }
}